// Round 14
// baseline (420.302 us; speedup 1.0000x reference)
//
#include <hip/hip_runtime.h>
#include <hip/hip_bf16.h>
#include <stdint.h>

#define NPTS 50000
#define NPAD 50048   // 391 * 128 row tiles

typedef unsigned short u16;
typedef __attribute__((ext_vector_type(8))) __bf16 bf16x8;
typedef __attribute__((ext_vector_type(4))) float f32x4;

__device__ __forceinline__ float bf2f(__hip_bfloat16 v) { return __bfloat162float(v); }
__device__ __forceinline__ __hip_bfloat16 f2bf(float v) { return __float2bfloat16(v); }
__device__ __forceinline__ float bfbits2f(unsigned short u) { return __uint_as_float(((unsigned)u) << 16); }
__device__ __forceinline__ unsigned short f2bfbits(float f) {
    __hip_bfloat16 h = f2bf(f);
    return *(unsigned short*)&h;
}
__device__ __forceinline__ int clampi(int v) { return v < 0 ? 0 : (v >= NPTS ? NPTS - 1 : v); }

__device__ __forceinline__ unsigned enc_f32(float f) {
    unsigned b = __float_as_uint(f);
    return (b & 0x80000000u) ? ~b : (b | 0x80000000u);
}
__device__ __forceinline__ float dec_f32(unsigned u) {
    return (u & 0x80000000u) ? __uint_as_float(u & 0x7fffffffu) : __uint_as_float(~u);
}

__device__ __forceinline__ void gload_lds16(const void* g, void* l) {
    __builtin_amdgcn_global_load_lds((__attribute__((address_space(1))) void*)g,
                                     (__attribute__((address_space(3))) void*)l, 16, 0, 0);
}

__device__ __forceinline__ ushort4 avg4(ushort4 a, ushort4 b, ushort4 c, ushort4 d) {
    ushort4 r;
    r.x = f2bfbits((bfbits2f(a.x) + bfbits2f(b.x) + bfbits2f(c.x) + bfbits2f(d.x)) * 0.25f);
    r.y = f2bfbits((bfbits2f(a.y) + bfbits2f(b.y) + bfbits2f(c.y) + bfbits2f(d.y)) * 0.25f);
    r.z = f2bfbits((bfbits2f(a.z) + bfbits2f(b.z) + bfbits2f(c.z) + bfbits2f(d.z)) * 0.25f);
    r.w = f2bfbits((bfbits2f(a.w) + bfbits2f(b.w) + bfbits2f(c.w) + bfbits2f(d.w)) * 0.25f);
    return r;
}

// avg of 4 packed bf16-pairs (low/high 16 bits)
__device__ __forceinline__ unsigned avgpair(unsigned a, unsigned b, unsigned c, unsigned d) {
    float lo = (bfbits2f(a & 0xffff) + bfbits2f(b & 0xffff) + bfbits2f(c & 0xffff) + bfbits2f(d & 0xffff)) * 0.25f;
    float hi = (bfbits2f(a >> 16) + bfbits2f(b >> 16) + bfbits2f(c >> 16) + bfbits2f(d >> 16)) * 0.25f;
    return (unsigned)f2bfbits(lo) | ((unsigned)f2bfbits(hi) << 16);
}

// ---------------------------------------------------------------------------
// wg_body: 64x64-tile fp32 GEMM body. C = A@B (+ D on cols<dcols); stores
// guarded by cidx<ncols; zf=1 writes bf16 zero into cols >= ncols.
// ---------------------------------------------------------------------------
__device__ __forceinline__ void wg_body(
    const float* A, int lda, const float* B, int ldb,
    const float* D, int ldd, int dcols,
    float* Cf, __hip_bfloat16* Cb, int ldc, int K, int ncols, int zf,
    int bj, int bi, int t, float (*sA)[68], float (*sB)[68])
{
    const int tx = t & 15, ty = t >> 4;
    float acc[4][4] = {};
    for (int k0 = 0; k0 < K; k0 += 16) {
        {
            int k = t & 15, m = t >> 4;
#pragma unroll
            for (int q = 0; q < 4; ++q)
                sA[k][m + q * 16] = A[(long)(bi * 64 + m + q * 16) * lda + k0 + k];
            int n = t & 63, kk = t >> 6;
#pragma unroll
            for (int q = 0; q < 4; ++q)
                sB[kk + q * 4][n] = B[(long)(k0 + kk + q * 4) * ldb + bj * 64 + n];
        }
        __syncthreads();
#pragma unroll
        for (int k = 0; k < 16; ++k) {
            f32x4 av = *(const f32x4*)&sA[k][ty * 4];
            f32x4 bv = *(const f32x4*)&sB[k][tx * 4];
#pragma unroll
            for (int i = 0; i < 4; ++i)
#pragma unroll
                for (int j = 0; j < 4; ++j)
                    acc[i][j] += av[i] * bv[j];
        }
        __syncthreads();
    }
#pragma unroll
    for (int i = 0; i < 4; ++i) {
        int r = bi * 64 + ty * 4 + i;
#pragma unroll
        for (int j = 0; j < 4; ++j) {
            int cidx = bj * 64 + tx * 4 + j;
            if (cidx >= ncols) {
                if (zf && Cb) Cb[(long)r * ldc + cidx] = f2bf(0.f);
                continue;
            }
            float v = acc[i][j];
            if (D && cidx < dcols) v += D[(long)r * ldd + cidx];
            if (Cf) Cf[(long)r * ldc + cidx] = v;
            if (Cb) Cb[(long)r * ldc + cidx] = f2bf(v);
        }
    }
}

// ---------------------------------------------------------------------------
// gather1: 4 points per wave, cat1 cols [64,224) -> agg1 (ld 160)
// ---------------------------------------------------------------------------
__device__ __forceinline__ void gather1_body4(
    const __hip_bfloat16* cat1, const int* neighbour, __hip_bfloat16* agg1,
    long pbase, int lane)
{
    if (lane >= 40) return;
    ushort4 va[4], vb[4], vc[4], vd[4];
#pragma unroll
    for (int q = 0; q < 4; ++q) {
        long p = pbase + q;
        if (p < NPTS) {
            int nb0 = clampi(neighbour[p * 3]), nb1 = clampi(neighbour[p * 3 + 1]), nb2 = clampi(neighbour[p * 3 + 2]);
            va[q] = ((const ushort4*)(cat1 + p * 224 + 64))[lane];
            vb[q] = ((const ushort4*)(cat1 + (long)nb0 * 224 + 64))[lane];
            vc[q] = ((const ushort4*)(cat1 + (long)nb1 * 224 + 64))[lane];
            vd[q] = ((const ushort4*)(cat1 + (long)nb2 * 224 + 64))[lane];
        }
    }
#pragma unroll
    for (int q = 0; q < 4; ++q) {
        long p = pbase + q;
        if (p >= NPAD) continue;
        ushort4* o = (ushort4*)(agg1 + p * 160);
        o[lane] = (p < NPTS) ? avg4(va[q], vb[q], vc[q], vd[q]) : make_ushort4(0, 0, 0, 0);
    }
}

// ---------------------------------------------------------------------------
// featurize body: cat1 row (ld 224) = [h1r(64)|h3r(64)|kc(64)|nrm(3)+pad]
// ---------------------------------------------------------------------------
__device__ void featurize_body(
    const float* centre, const float* corner, const float* normal,
    const int* neighbour,
    const float* W_sp2, const float* b_sp2, const float* conv_w, const float* conv_b,
    const float* W_fr3, const float* b_fr3, const float* theta, const float* phi,
    __hip_bfloat16* cat1, int bid, int nblocks)
{
    __shared__ float sWsp2t[3][64];  __shared__ float sbsp2[64];
    __shared__ float sconvt[6][32];  __shared__ float sconvb[32];
    __shared__ float sWfr3t[32][64]; __shared__ float sbfr3[64];
    __shared__ float kt4x[4][64], kt4y[4][64], kt4z[4][64];

    const int tid = threadIdx.x;
    for (int i = tid; i < 2048; i += 256) { int j = i >> 5, k = i & 31; sWfr3t[k][j] = W_fr3[i]; }
    for (int i = tid; i < 192; i += 256) { int j = i / 3, k = i % 3; sWsp2t[k][j] = W_sp2[i]; }
    for (int i = tid; i < 192; i += 256) { int o = i / 6, k = i % 6; sconvt[k][o] = conv_w[i]; }
    if (tid < 64) { sbsp2[tid] = b_sp2[tid]; sbfr3[tid] = b_fr3[tid]; }
    if (tid < 32) sconvb[tid] = conv_b[tid];
    {
        int j = tid >> 2, s = tid & 3;
        float th = theta[tid], ph = phi[tid];
        float st = sinf(th), ct = cosf(th), sp = sinf(ph), cp = cosf(ph);
        kt4x[s][j] = st * sp; kt4y[s][j] = st * cp; kt4z[s][j] = ct;
    }
    __syncthreads();

    const int lane = tid & 63, wave = tid >> 6;
    for (long p = (long)bid * 4 + wave; p < NPAD; p += (long)nblocks * 4) {
        __hip_bfloat16* row = cat1 + p * 224;
        if (p >= NPTS) {
            __hip_bfloat16 z = f2bf(0.f);
            row[lane] = z; row[64 + lane] = z; row[128 + lane] = z;
            if (lane < 32) row[192 + lane] = z;
            continue;
        }
        float cx = centre[p * 3], cy = centre[p * 3 + 1], cz = centre[p * 3 + 2];
        float h1r = fmaxf(sbsp2[lane] + cx * sWsp2t[0][lane] + cy * sWsp2t[1][lane]
                          + cz * sWsp2t[2][lane], 0.f);
        float mval = 0.f;
        if (lane < 32) {
            float c0 = corner[p*9+0], c1 = corner[p*9+1], c2 = corner[p*9+2];
            float c3 = corner[p*9+3], c4 = corner[p*9+4], c5 = corner[p*9+5];
            float c6 = corner[p*9+6], c7 = corner[p*9+7], c8 = corner[p*9+8];
            float s0 = c0 + c3 + c6, s1 = c1 + c4 + c7, s2 = c2 + c5 + c8;
            mval = sconvb[lane] + (1.f / 3.f) *
                ((sconvt[0][lane] + sconvt[3][lane]) * s0 +
                 (sconvt[1][lane] + sconvt[4][lane]) * s1 +
                 (sconvt[2][lane] + sconvt[5][lane]) * s2);
        }
        float h3 = sbfr3[lane];
#pragma unroll 8
        for (int k = 0; k < 32; ++k) h3 += __shfl(mval, k) * sWfr3t[k][lane];
        float h3r = fmaxf(h3, 0.f);
        int nb0 = clampi(neighbour[p * 3]), nb1 = clampi(neighbour[p * 3 + 1]), nb2 = clampi(neighbour[p * 3 + 2]);
        float nx[4], ny[4], nz[4];
        nx[0] = normal[p * 3];          ny[0] = normal[p * 3 + 1];          nz[0] = normal[p * 3 + 2];
        nx[1] = normal[(long)nb0 * 3];  ny[1] = normal[(long)nb0 * 3 + 1];  nz[1] = normal[(long)nb0 * 3 + 2];
        nx[2] = normal[(long)nb1 * 3];  ny[2] = normal[(long)nb1 * 3 + 1];  nz[2] = normal[(long)nb1 * 3 + 2];
        nx[3] = normal[(long)nb2 * 3];  ny[3] = normal[(long)nb2 * 3 + 1];  nz[3] = normal[(long)nb2 * 3 + 2];
        float kcs = 0.f;
#pragma unroll
        for (int s = 0; s < 4; ++s) {
            float kx = kt4x[s][lane], ky = kt4y[s][lane], kz = kt4z[s][lane];
#pragma unroll
            for (int t = 0; t < 4; ++t) {
                float dx = nx[t] - kx, dy = ny[t] - ky, dz = nz[t] - kz;
                kcs += __expf(-12.5f * (dx * dx + dy * dy + dz * dz));
            }
        }
        float kcv = kcs * (1.f / 16.f);
        row[lane] = f2bf(h1r); row[64 + lane] = f2bf(h3r); row[128 + lane] = f2bf(kcv);
        if (lane < 32) {
            float nrmv = (lane == 0) ? nx[0] : (lane == 1) ? ny[0] : (lane == 2) ? nz[0] : 0.f;
            row[192 + lane] = f2bf(nrmv);
        }
    }
}

// ---------------------------------------------------------------------------
// combo1: b<644 fold work + g_enc init || b>=644 featurize (2048 blocks)
// ---------------------------------------------------------------------------
__global__ __launch_bounds__(256) void combo1(
    const float* __restrict__ W_c1, const float* __restrict__ W_a1,
    const float* __restrict__ W_sp1, const float* __restrict__ W_fr4,
    const float* __restrict__ W_f,
    const float* __restrict__ b_sp1, const float* __restrict__ b_fr4,
    const float* __restrict__ b_c1, const float* __restrict__ b_a1,
    const float* __restrict__ b_f, const float* __restrict__ b_a2,
    float* __restrict__ Wc1ff, float* __restrict__ Wa1ff,
    float* __restrict__ bc1v, float* __restrict__ b_a1p, float* __restrict__ w2,
    unsigned* __restrict__ g_enc,
    const float* __restrict__ centre, const float* __restrict__ corner,
    const float* __restrict__ normal, const int* __restrict__ neighbour,
    const float* __restrict__ W_sp2, const float* __restrict__ b_sp2,
    const float* __restrict__ conv_w, const float* __restrict__ conv_b,
    const float* __restrict__ W_fr3, const float* __restrict__ b_fr3,
    const float* __restrict__ theta, const float* __restrict__ phi,
    __hip_bfloat16* __restrict__ cat1)
{
    const int b = blockIdx.x, t = threadIdx.x;
    if (b >= 644) {
        featurize_body(centre, corner, normal, neighbour, W_sp2, b_sp2,
                       conv_w, conv_b, W_fr3, b_fr3, theta, phi, cat1, b - 644, 2048);
        return;
    }
    if (b < 256) {
        const int r = b;
        float vc, va;
        if (t < 64) {
            float s = 0.f;
            for (int k = 0; k < 64; ++k) s += W_c1[r * 195 + k] * W_sp1[k * 64 + t];
            vc = s;
            s = 0.f;
            for (int k = 0; k < 64; ++k) s += W_a1[r * 131 + k] * W_fr4[k * 64 + t];
            va = s;
        } else if (t < 128) {
            float s = 0.f;
            for (int k = 0; k < 64; ++k) s += W_c1[r * 195 + 64 + k] * W_fr4[k * 64 + (t - 64)];
            vc = s;
            va = W_a1[r * 131 + t];
        } else {
            vc = (t < 195) ? W_c1[r * 195 + t] : 0.f;
            va = (t < 131) ? W_a1[r * 131 + t] : 0.f;
        }
        Wc1ff[r * 256 + t] = vc;
        Wa1ff[r * 256 + t] = va;
    } else if (b < 640) {
        int o = (b - 256) * 4 + (t >> 6);
        int lane = t & 63;
        float a = 0.f;
        if (o < 256) {
            a = W_c1[o * 195 + lane] * b_sp1[lane] + W_c1[o * 195 + 64 + lane] * b_fr4[lane];
        } else if (o < 512) {
            a = W_a1[(o - 256) * 131 + lane] * b_fr4[lane];
        } else {
            for (int k = lane; k < 512; k += 64) a += W_f[(long)(o - 512) * 1024 + 512 + k] * b_a2[k];
        }
#pragma unroll
        for (int off = 32; off > 0; off >>= 1) a += __shfl_xor(a, off);
        if (lane == 0) {
            if (o < 256)      bc1v[o] = b_c1[o] + a;
            else if (o < 512) b_a1p[o - 256] = b_a1[o - 256] + a;
            else              w2[o - 512] = b_f[o - 512] + a;
        }
    } else {
        g_enc[(b - 640) * 256 + t] = 0x007FFFFFu;
    }
}

// ---------------------------------------------------------------------------
// combo2: id<192 -> L1 (T3 = M3@Wfa + M2 (8 colblk) || B2f = Wfb@W_a2 (4))
//         else   -> gather1 slice starting at p0
// ---------------------------------------------------------------------------
__global__ __launch_bounds__(256) void combo2(
    const float* __restrict__ W_m2, const float* __restrict__ W_f,
    const float* __restrict__ W_a2,
    float* __restrict__ T3f, float* __restrict__ B2f,
    const __hip_bfloat16* __restrict__ cat1, const int* __restrict__ neighbour,
    __hip_bfloat16* __restrict__ agg1, long p0)
{
    const int id = blockIdx.x, t = threadIdx.x;
    if (id < 192) {
        __shared__ float sA[16][68], sB[16][68];
        int bj = id % 12, bi = id / 12;
        if (bj < 8)
            wg_body(W_m2 + 768, 1792, W_f, 1024, W_m2 + 256, 1792, 512,
                    T3f, (__hip_bfloat16*)nullptr, 512, 1024, 512, 0, bj, bi, t, sA, sB);
        else
            wg_body(W_f + 512, 1024, W_a2, 256, (const float*)nullptr, 0, 0,
                    B2f, (__hip_bfloat16*)nullptr, 256, 512, 256, 0, bj - 8, bi, t, sA, sB);
    } else {
        long pbase = p0 + (long)(id - 192) * 16 + (t >> 6) * 4;
        gather1_body4(cat1, neighbour, agg1, pbase, t & 63);
    }
}

// ---------------------------------------------------------------------------
// combo3: id<192 -> L2 (U = T3@W_c2 + [M1|0] (8 colblk) || Vf = M3@B2f (4))
//         else   -> gather1 slice starting at p0
// ---------------------------------------------------------------------------
__global__ __launch_bounds__(256) void combo3(
    const float* __restrict__ T3f, const float* __restrict__ W_c2,
    const float* __restrict__ W_m2, const float* __restrict__ B2f,
    float* __restrict__ Uf, float* __restrict__ Vf,
    const __hip_bfloat16* __restrict__ cat1, const int* __restrict__ neighbour,
    __hip_bfloat16* __restrict__ agg1, long p0)
{
    const int id = blockIdx.x, t = threadIdx.x;
    if (id < 192) {
        __shared__ float sA[16][68], sB[16][68];
        int bj = id % 12, bi = id / 12;
        if (bj < 8)
            wg_body(T3f, 512, W_c2, 512, W_m2, 1792, 256,
                    Uf, (__hip_bfloat16*)nullptr, 512, 512, 512, 0, bj, bi, t, sA, sB);
        else
            wg_body(W_m2 + 768, 1792, B2f, 256, (const float*)nullptr, 0, 0,
                    Vf, (__hip_bfloat16*)nullptr, 256, 1024, 256, 0, bj - 8, bi, t, sA, sB);
    } else {
        long pbase = p0 + (long)(id - 192) * 16 + (t >> 6) * 4;
        gather1_body4(cat1, neighbour, agg1, pbase, t & 63);
    }
}

// ---------------------------------------------------------------------------
// l4: id<416 -> X1'/X2'/V' -> Xw, cvec; else gather1 slice starting at p0
// ---------------------------------------------------------------------------
__global__ __launch_bounds__(256) void l4(
    const float* __restrict__ Uf, const float* __restrict__ Vf,
    const float* __restrict__ Wc1ff, const float* __restrict__ Wa1ff,
    __hip_bfloat16* __restrict__ Xw,
    const float* __restrict__ W_m2, const float* __restrict__ T3f,
    const float* __restrict__ w2, const float* __restrict__ b_c2,
    const float* __restrict__ bc1v, const float* __restrict__ b_a1p,
    float* __restrict__ cvec,
    const __hip_bfloat16* __restrict__ cat1, const int* __restrict__ neighbour,
    __hip_bfloat16* __restrict__ agg1, long p0)
{
    const int id = blockIdx.x, t = threadIdx.x;
    if (id >= 416) {
        long pbase = p0 + (long)(id - 416) * 16 + (t >> 6) * 4;
        gather1_body4(cat1, neighbour, agg1, pbase, t & 63);
        return;
    }
    __shared__ float sA[16][68], sB[16][68];
    const int bx = id % 26, bi = id / 26;
    if (bx < 4) {
        wg_body(Uf, 512, Wc1ff, 256, (const float*)nullptr, 0, 0,
                (float*)nullptr, Xw, 576, 256, 224, 0, bx, bi, t, sA, sB);
    } else if (bx < 7) {
        wg_body(Uf + 256, 512, Wa1ff, 256, (const float*)nullptr, 0, 0,
                (float*)nullptr, Xw + 224, 576, 256, 160, 0, bx - 4, bi, t, sA, sB);
    } else if (bx < 10) {
        wg_body(Vf, 256, Wa1ff, 256, (const float*)nullptr, 0, 0,
                (float*)nullptr, Xw + 384, 576, 256, 160, 0, bx - 7, bi, t, sA, sB);
    } else {
        int i = ((bx - 10) * 16 + bi) * 4 + (t >> 6);
        int lane = t & 63;
        const float* m3row = W_m2 + (long)i * 1792 + 768;
        float a = 0.f;
        for (int k = lane; k < 1024; k += 64) a += w2[k] * m3row[k];
        for (int k = lane; k < 512;  k += 64) a += b_c2[k] * T3f[(long)i * 512 + k];
        for (int k = lane; k < 256;  k += 64) a += bc1v[k] * Uf[(long)i * 512 + k];
        for (int k = lane; k < 256;  k += 64) a += b_a1p[k] * Uf[(long)i * 512 + 256 + k];
        for (int k = lane; k < 256;  k += 64) a += b_a1p[k] * Vf[(long)i * 256 + k];
#pragma unroll
        for (int off = 32; off > 0; off >>= 1) a += __shfl_xor(a, off);
        if (lane == 0) cvec[i] = a;
    }
}

// ---------------------------------------------------------------------------
// max-GEMM K=544: A = [cat1(224) | agg1(160) | 2hop(agg1)(160)], B=Xw(ld576).
// The 2-hop segment (kh in [384,544)) is gathered on the fly from agg1 using
// per-row neighbor indices (fused gather1t). XCD-swizzled grid keeps the
// gathered rows L2-resident across the row-tile's 8 column passes.
// ---------------------------------------------------------------------------
__global__ __launch_bounds__(256) void gemm_nt_max544(
    const __hip_bfloat16* __restrict__ A0,   // cat1, ld 224
    const __hip_bfloat16* __restrict__ A1,   // agg1, ld 160
    const int* __restrict__ neighbour,
    const __hip_bfloat16* __restrict__ B,    // Xw, ld 576
    unsigned* __restrict__ g_enc)
{
    __shared__ __align__(16) u16 Asm[2 * 128 * 32];
    __shared__ __align__(16) u16 Bsm[2 * 128 * 32];
    __shared__ float red[2][128];
    const int id = blockIdx.x;
    const int c = id & 7, tt = id >> 3;
    const int j8 = tt & 7, rh = tt >> 3;
    const int r = rh * 8 + c;
    if (r >= NPAD / 128) return;
    const long rowbase = (long)r * 128;
    const int colbase = j8 * 128;
    const int tid = threadIdx.x;
    const int lane = tid & 63, wave = tid >> 6;
    const int wr = wave >> 1, wc = wave & 1;
    const int m16 = lane & 15, kg = lane >> 4;
    const int srow = tid >> 2, skc = tid & 3;
    // preload neighbor indices for this thread's two staging rows
    int nbi[2][3]; bool pval[2];
#pragma unroll
    for (int i = 0; i < 2; ++i) {
        long p = rowbase + srow + i * 64;
        pval[i] = (p < NPTS);
        if (pval[i]) {
            nbi[i][0] = clampi(neighbour[p * 3]);
            nbi[i][1] = clampi(neighbour[p * 3 + 1]);
            nbi[i][2] = clampi(neighbour[p * 3 + 2]);
        } else {
            nbi[i][0] = nbi[i][1] = nbi[i][2] = 0;
        }
    }
    f32x4 acc[4][4] = {};
#pragma unroll
    for (int kt = 0; kt < 544; kt += 64) {
        const int nh = (kt + 64 <= 544) ? 2 : 1;   // compile-time per unrolled kt
#pragma unroll
        for (int h = 0; h < 2; ++h) {
            if (h >= nh) break;
            const int kh = kt + h * 32;
#pragma unroll
            for (int i = 0; i < 2; ++i) {
                const int cid = i * 256 + tid;
                const int row = srow + i * 64;
                gload_lds16(B + (long)(colbase + row) * 576 + kh + skc * 8, Bsm + h * 4096 + cid * 8);
                if (kh < 224) {
                    gload_lds16(A0 + (rowbase + row) * 224 + kh + skc * 8, Asm + h * 4096 + cid * 8);
                } else if (kh < 384) {
                    gload_lds16(A1 + (rowbase + row) * 160 + (kh - 224) + skc * 8, Asm + h * 4096 + cid * 8);
                } else {
                    // fused 2-hop gather: avg of agg1 rows {p, nb0, nb1, nb2}
                    const int col = (kh - 384) + skc * 8;   // < 160 always
                    uint4 v;
                    if (pval[i]) {
                        long p = rowbase + row;
                        uint4 a = *(const uint4*)(A1 + p * 160 + col);
                        uint4 b = *(const uint4*)(A1 + (long)nbi[i][0] * 160 + col);
                        uint4 cc = *(const uint4*)(A1 + (long)nbi[i][1] * 160 + col);
                        uint4 d = *(const uint4*)(A1 + (long)nbi[i][2] * 160 + col);
                        v.x = avgpair(a.x, b.x, cc.x, d.x);
                        v.y = avgpair(a.y, b.y, cc.y, d.y);
                        v.z = avgpair(a.z, b.z, cc.z, d.z);
                        v.w = avgpair(a.w, b.w, cc.w, d.w);
                    } else {
                        v = make_uint4(0, 0, 0, 0);
                    }
                    *(uint4*)(Asm + h * 4096 + cid * 8) = v;
                }
            }
        }
        __syncthreads();
#pragma unroll
        for (int h = 0; h < 2; ++h) {
            if (h >= nh) break;
            bf16x8 af[4], bv[4];
#pragma unroll
            for (int i = 0; i < 4; ++i)
                af[i] = *(const bf16x8*)(Asm + h * 4096 + ((wr * 64 + i * 16 + m16) * 32 + kg * 8));
#pragma unroll
            for (int j = 0; j < 4; ++j)
                bv[j] = *(const bf16x8*)(Bsm + h * 4096 + ((wc * 64 + j * 16 + m16) * 32 + kg * 8));
#pragma unroll
            for (int i = 0; i < 4; ++i)
#pragma unroll
                for (int j = 0; j < 4; ++j)
                    acc[i][j] = __builtin_amdgcn_mfma_f32_16x16x32_bf16(af[i], bv[j], acc[i][j], 0, 0, 0);
        }
        __syncthreads();
    }
    const int q = lane >> 4;
#pragma unroll
    for (int j = 0; j < 4; ++j) {
        float m = -INFINITY;
#pragma unroll
        for (int i = 0; i < 4; ++i)
#pragma unroll
            for (int rr = 0; rr < 4; ++rr) {
                long rowg = rowbase + wr * 64 + i * 16 + q * 4 + rr;
                m = (rowg < NPTS) ? fmaxf(m, acc[i][j][rr]) : m;
            }
        m = fmaxf(m, __shfl_xor(m, 16));
        m = fmaxf(m, __shfl_xor(m, 32));
        if (lane < 16) red[wr][wc * 64 + j * 16 + m16] = m;
    }
    __syncthreads();
    if (tid < 128) {
        float v = fmaxf(red[0][tid], red[1][tid]);
        atomicMax(g_enc + colbase + tid, enc_f32(v));
    }
}

// ---------------------------------------------------------------------------
// head
// ---------------------------------------------------------------------------
__global__ __launch_bounds__(256) void head_lin_g(
    const unsigned* __restrict__ g_enc, const float* __restrict__ cvec,
    const float* __restrict__ b_m2,
    const float* __restrict__ W, const float* __restrict__ b,
    float* __restrict__ out)
{
    int o = blockIdx.x * 4 + (threadIdx.x >> 6);
    int lane = threadIdx.x & 63;
    if (o >= 512) return;
    float a = 0.f;
    for (int k = lane; k < 1024; k += 64) {
        float g = dec_f32(g_enc[k]) + cvec[k] + b_m2[k];
        a += g * W[(long)o * 1024 + k];
    }
#pragma unroll
    for (int off = 32; off > 0; off >>= 1) a += __shfl_xor(a, off);
    if (lane == 0) out[o] = fmaxf(a + b[o], 0.f);
}

__global__ __launch_bounds__(256) void head_lin(
    const float* __restrict__ in, const float* __restrict__ W,
    const float* __restrict__ b, float* __restrict__ out,
    int In, int Out, int do_relu)
{
    int o = blockIdx.x * 4 + (threadIdx.x >> 6);
    int lane = threadIdx.x & 63;
    if (o >= Out) return;
    float a = 0.f;
    for (int k = lane; k < In; k += 64) a += in[k] * W[(long)o * In + k];
#pragma unroll
    for (int off = 32; off > 0; off >>= 1) a += __shfl_xor(a, off);
    if (lane == 0) {
        float v = a + b[o];
        out[o] = do_relu ? fmaxf(v, 0.f) : v;
    }
}

// ---------------------------------------------------------------------------
extern "C" void kernel_launch(void* const* d_in, const int* in_sizes, int n_in,
                              void* d_out, int out_size, void* d_ws, size_t ws_size,
                              hipStream_t stream)
{
    (void)in_sizes; (void)n_in; (void)out_size; (void)ws_size;
    const float* centre = (const float*)d_in[0];
    const float* corner = (const float*)d_in[1];
    const float* normal = (const float*)d_in[2];
    const int*   neighbour = (const int*)d_in[3];
    const float* W_sp2 = (const float*)d_in[4];
    const float* b_sp2 = (const float*)d_in[5];
    const float* W_sp1 = (const float*)d_in[6];
    const float* b_sp1 = (const float*)d_in[7];
    const float* conv_w = (const float*)d_in[8];
    const float* conv_b = (const float*)d_in[9];
    const float* W_fr3 = (const float*)d_in[10];
    const float* b_fr3 = (const float*)d_in[11];
    const float* W_fr4 = (const float*)d_in[12];
    const float* b_fr4 = (const float*)d_in[13];
    const float* theta = (const float*)d_in[14];
    const float* phi   = (const float*)d_in[15];
    const float* W_c1 = (const float*)d_in[16];
    const float* b_c1 = (const float*)d_in[17];
    const float* W_a1 = (const float*)d_in[18];
    const float* b_a1 = (const float*)d_in[19];
    const float* W_c2 = (const float*)d_in[20];
    const float* b_c2 = (const float*)d_in[21];
    const float* W_a2 = (const float*)d_in[22];
    const float* b_a2 = (const float*)d_in[23];
    const float* W_f  = (const float*)d_in[24];
    const float* b_f  = (const float*)d_in[25];
    const float* W_m2 = (const float*)d_in[26];
    const float* b_m2 = (const float*)d_in[27];
    const float* W_m31 = (const float*)d_in[28];
    const float* b_m31 = (const float*)d_in[29];
    const float* W_m32 = (const float*)d_in[30];
    const float* b_m32 = (const float*)d_in[31];
    const float* W_m33 = (const float*)d_in[32];
    const float* b_m33 = (const float*)d_in[33];

    char* ws = (char*)d_ws;
    size_t off = 0;
    auto alloc = [&](size_t bytes) { void* p = ws + off; off += (bytes + 255) & ~(size_t)255; return p; };
    __hip_bfloat16* cat1  = (__hip_bfloat16*)alloc((size_t)NPAD * 224 * 2);  // [h1r|h3r|kc|nrm+pad]
    __hip_bfloat16* agg1  = (__hip_bfloat16*)alloc((size_t)NPAD * 160 * 2);  // 1-hop avg
    float* Wc1ff = (float*)alloc((size_t)65536 * 4);
    float* Wa1ff = (float*)alloc((size_t)65536 * 4);
    __hip_bfloat16* Xw = (__hip_bfloat16*)alloc((size_t)1024 * 576 * 2);     // [X1'(224)|X2'(160)|V'(160)|unused(32)]
    float* T3f  = (float*)alloc((size_t)1024 * 512 * 4);
    float* Uf   = (float*)alloc((size_t)1024 * 512 * 4);                     // [U1|U2]
    float* B2f  = (float*)alloc((size_t)1024 * 256 * 4);
    float* Vf   = (float*)alloc((size_t)1024 * 256 * 4);
    float* bc1v = (float*)alloc(256 * 4);
    float* b_a1p = (float*)alloc(256 * 4);
    float* w2   = (float*)alloc(1024 * 4);
    float* cvec = (float*)alloc(1024 * 4);
    unsigned* g_enc = (unsigned*)alloc(1024 * 4);
    float* h1   = (float*)alloc(512 * 4);
    float* h2   = (float*)alloc(256 * 4);

    // 1) folds + g_enc init || featurize
    combo1<<<2692, 256, 0, stream>>>(W_c1, W_a1, W_sp1, W_fr4, W_f,
        b_sp1, b_fr4, b_c1, b_a1, b_f, b_a2,
        Wc1ff, Wa1ff, bc1v, b_a1p, w2, g_enc,
        centre, corner, normal, neighbour, W_sp2, b_sp2,
        conv_w, conv_b, W_fr3, b_fr3, theta, phi, cat1);
    // 2) L1 (T3, B2f) || gather1 points [0, 16688)
    combo2<<<192 + 1043, 256, 0, stream>>>(W_m2, W_f, W_a2, T3f, B2f,
        cat1, neighbour, agg1, 0L);
    // 3) L2 (U, Vf) || gather1 points [16688, 33376)
    combo3<<<192 + 1043, 256, 0, stream>>>(T3f, W_c2, W_m2, B2f, Uf, Vf,
        cat1, neighbour, agg1, 16688L);
    // 4) X1'/X2'/V' -> Xw + cvec || gather1 points [33376, NPAD)
    l4<<<416 + 1043, 256, 0, stream>>>(Uf, Vf, Wc1ff, Wa1ff, Xw,
        W_m2, T3f, w2, b_c2, bc1v, b_a1p, cvec,
        cat1, neighbour, agg1, 33376L);
    // 5) g = max_n([cat1|agg1|2hop(agg1)] @ Xw^T), K=544, fused 2-hop gather
    gemm_nt_max544<<<3136, 256, 0, stream>>>(cat1, agg1, neighbour, Xw, g_enc);
    // 6-8) head
    head_lin_g<<<128, 256, 0, stream>>>(g_enc, cvec, b_m2, W_m31, b_m31, h1);
    head_lin<<<64, 256, 0, stream>>>(h1, W_m32, b_m32, h2, 512, 256, 1);
    head_lin<<<10, 256, 0, stream>>>(h2, W_m33, b_m33, (float*)d_out, 256, 40, 0);
}

// Round 16
// 345.955 us; speedup vs baseline: 1.2149x; 1.2149x over previous
//
#include <hip/hip_runtime.h>
#include <hip/hip_bf16.h>
#include <stdint.h>

#define NPTS 50000
#define NPAD 50048   // 391 * 128 row tiles

typedef unsigned short u16;
typedef __attribute__((ext_vector_type(8))) __bf16 bf16x8;
typedef __attribute__((ext_vector_type(4))) float f32x4;

__device__ __forceinline__ float bf2f(__hip_bfloat16 v) { return __bfloat162float(v); }
__device__ __forceinline__ __hip_bfloat16 f2bf(float v) { return __float2bfloat16(v); }
__device__ __forceinline__ float bfbits2f(unsigned short u) { return __uint_as_float(((unsigned)u) << 16); }
__device__ __forceinline__ unsigned short f2bfbits(float f) {
    __hip_bfloat16 h = f2bf(f);
    return *(unsigned short*)&h;
}
__device__ __forceinline__ int clampi(int v) { return v < 0 ? 0 : (v >= NPTS ? NPTS - 1 : v); }

__device__ __forceinline__ unsigned enc_f32(float f) {
    unsigned b = __float_as_uint(f);
    return (b & 0x80000000u) ? ~b : (b | 0x80000000u);
}
__device__ __forceinline__ float dec_f32(unsigned u) {
    return (u & 0x80000000u) ? __uint_as_float(u & 0x7fffffffu) : __uint_as_float(~u);
}

__device__ __forceinline__ void gload_lds16(const void* g, void* l) {
    __builtin_amdgcn_global_load_lds((__attribute__((address_space(1))) void*)g,
                                     (__attribute__((address_space(3))) void*)l, 16, 0, 0);
}

__device__ __forceinline__ ushort4 avg4(ushort4 a, ushort4 b, ushort4 c, ushort4 d) {
    ushort4 r;
    r.x = f2bfbits((bfbits2f(a.x) + bfbits2f(b.x) + bfbits2f(c.x) + bfbits2f(d.x)) * 0.25f);
    r.y = f2bfbits((bfbits2f(a.y) + bfbits2f(b.y) + bfbits2f(c.y) + bfbits2f(d.y)) * 0.25f);
    r.z = f2bfbits((bfbits2f(a.z) + bfbits2f(b.z) + bfbits2f(c.z) + bfbits2f(d.z)) * 0.25f);
    r.w = f2bfbits((bfbits2f(a.w) + bfbits2f(b.w) + bfbits2f(c.w) + bfbits2f(d.w)) * 0.25f);
    return r;
}

// ---------------------------------------------------------------------------
// wg_body: 64x64-tile fp32 GEMM body. C = A@B (+ D on cols<dcols); stores
// guarded by cidx<ncols; zf=1 writes bf16 zero into cols >= ncols.
// ---------------------------------------------------------------------------
__device__ __forceinline__ void wg_body(
    const float* A, int lda, const float* B, int ldb,
    const float* D, int ldd, int dcols,
    float* Cf, __hip_bfloat16* Cb, int ldc, int K, int ncols, int zf,
    int bj, int bi, int t, float (*sA)[68], float (*sB)[68])
{
    const int tx = t & 15, ty = t >> 4;
    float acc[4][4] = {};
    for (int k0 = 0; k0 < K; k0 += 16) {
        {
            int k = t & 15, m = t >> 4;
#pragma unroll
            for (int q = 0; q < 4; ++q)
                sA[k][m + q * 16] = A[(long)(bi * 64 + m + q * 16) * lda + k0 + k];
            int n = t & 63, kk = t >> 6;
#pragma unroll
            for (int q = 0; q < 4; ++q)
                sB[kk + q * 4][n] = B[(long)(k0 + kk + q * 4) * ldb + bj * 64 + n];
        }
        __syncthreads();
#pragma unroll
        for (int k = 0; k < 16; ++k) {
            f32x4 av = *(const f32x4*)&sA[k][ty * 4];
            f32x4 bv = *(const f32x4*)&sB[k][tx * 4];
#pragma unroll
            for (int i = 0; i < 4; ++i)
#pragma unroll
                for (int j = 0; j < 4; ++j)
                    acc[i][j] += av[i] * bv[j];
        }
        __syncthreads();
    }
#pragma unroll
    for (int i = 0; i < 4; ++i) {
        int r = bi * 64 + ty * 4 + i;
#pragma unroll
        for (int j = 0; j < 4; ++j) {
            int cidx = bj * 64 + tx * 4 + j;
            if (cidx >= ncols) {
                if (zf && Cb) Cb[(long)r * ldc + cidx] = f2bf(0.f);
                continue;
            }
            float v = acc[i][j];
            if (D && cidx < dcols) v += D[(long)r * ldd + cidx];
            if (Cf) Cf[(long)r * ldc + cidx] = v;
            if (Cb) Cb[(long)r * ldc + cidx] = f2bf(v);
        }
    }
}

// ---------------------------------------------------------------------------
// gather bodies: 4 points per wave
// ---------------------------------------------------------------------------
__device__ __forceinline__ void gather1_body4(
    const __hip_bfloat16* cat1, const int* neighbour, __hip_bfloat16* agg1,
    long pbase, int lane)
{
    if (lane >= 40) return;
    ushort4 va[4], vb[4], vc[4], vd[4];
#pragma unroll
    for (int q = 0; q < 4; ++q) {
        long p = pbase + q;
        if (p < NPTS) {
            int nb0 = clampi(neighbour[p * 3]), nb1 = clampi(neighbour[p * 3 + 1]), nb2 = clampi(neighbour[p * 3 + 2]);
            va[q] = ((const ushort4*)(cat1 + p * 224 + 64))[lane];
            vb[q] = ((const ushort4*)(cat1 + (long)nb0 * 224 + 64))[lane];
            vc[q] = ((const ushort4*)(cat1 + (long)nb1 * 224 + 64))[lane];
            vd[q] = ((const ushort4*)(cat1 + (long)nb2 * 224 + 64))[lane];
        }
    }
#pragma unroll
    for (int q = 0; q < 4; ++q) {
        long p = pbase + q;
        if (p >= NPAD) continue;
        ushort4* o = (ushort4*)(agg1 + p * 160);
        o[lane] = (p < NPTS) ? avg4(va[q], vb[q], vc[q], vd[q]) : make_ushort4(0, 0, 0, 0);
    }
}

// agg1t (ld 192): 2-hop avg of agg1 (ld 160); lanes 40..47 zero the pad cols
__device__ __forceinline__ void gather1t_body4(
    const __hip_bfloat16* agg1, const int* neighbour, __hip_bfloat16* agg1t,
    long pbase, int lane)
{
    if (lane >= 48) return;
    if (lane >= 40) {
#pragma unroll
        for (int q = 0; q < 4; ++q) {
            long p = pbase + q;
            if (p < NPAD) ((ushort4*)(agg1t + p * 192))[lane] = make_ushort4(0, 0, 0, 0);
        }
        return;
    }
    ushort4 va[4], vb[4], vc[4], vd[4];
#pragma unroll
    for (int q = 0; q < 4; ++q) {
        long p = pbase + q;
        if (p < NPTS) {
            int nb0 = clampi(neighbour[p * 3]), nb1 = clampi(neighbour[p * 3 + 1]), nb2 = clampi(neighbour[p * 3 + 2]);
            va[q] = ((const ushort4*)(agg1 + p * 160))[lane];
            vb[q] = ((const ushort4*)(agg1 + (long)nb0 * 160))[lane];
            vc[q] = ((const ushort4*)(agg1 + (long)nb1 * 160))[lane];
            vd[q] = ((const ushort4*)(agg1 + (long)nb2 * 160))[lane];
        }
    }
#pragma unroll
    for (int q = 0; q < 4; ++q) {
        long p = pbase + q;
        if (p >= NPAD) continue;
        ushort4* o = (ushort4*)(agg1t + p * 192);
        o[lane] = (p < NPTS) ? avg4(va[q], vb[q], vc[q], vd[q]) : make_ushort4(0, 0, 0, 0);
    }
}

// ---------------------------------------------------------------------------
// featurize body: cat1 row (ld 224) = [h1r(64)|h3r(64)|kc(64)|nrm(3)+pad]
// ---------------------------------------------------------------------------
__device__ void featurize_body(
    const float* centre, const float* corner, const float* normal,
    const int* neighbour,
    const float* W_sp2, const float* b_sp2, const float* conv_w, const float* conv_b,
    const float* W_fr3, const float* b_fr3, const float* theta, const float* phi,
    __hip_bfloat16* cat1, int bid, int nblocks)
{
    __shared__ float sWsp2t[3][64];  __shared__ float sbsp2[64];
    __shared__ float sconvt[6][32];  __shared__ float sconvb[32];
    __shared__ float sWfr3t[32][64]; __shared__ float sbfr3[64];
    __shared__ float kt4x[4][64], kt4y[4][64], kt4z[4][64];

    const int tid = threadIdx.x;
    for (int i = tid; i < 2048; i += 256) { int j = i >> 5, k = i & 31; sWfr3t[k][j] = W_fr3[i]; }
    for (int i = tid; i < 192; i += 256) { int j = i / 3, k = i % 3; sWsp2t[k][j] = W_sp2[i]; }
    for (int i = tid; i < 192; i += 256) { int o = i / 6, k = i % 6; sconvt[k][o] = conv_w[i]; }
    if (tid < 64) { sbsp2[tid] = b_sp2[tid]; sbfr3[tid] = b_fr3[tid]; }
    if (tid < 32) sconvb[tid] = conv_b[tid];
    {
        int j = tid >> 2, s = tid & 3;
        float th = theta[tid], ph = phi[tid];
        float st = sinf(th), ct = cosf(th), sp = sinf(ph), cp = cosf(ph);
        kt4x[s][j] = st * sp; kt4y[s][j] = st * cp; kt4z[s][j] = ct;
    }
    __syncthreads();

    const int lane = tid & 63, wave = tid >> 6;
    for (long p = (long)bid * 4 + wave; p < NPAD; p += (long)nblocks * 4) {
        __hip_bfloat16* row = cat1 + p * 224;
        if (p >= NPTS) {
            __hip_bfloat16 z = f2bf(0.f);
            row[lane] = z; row[64 + lane] = z; row[128 + lane] = z;
            if (lane < 32) row[192 + lane] = z;
            continue;
        }
        float cx = centre[p * 3], cy = centre[p * 3 + 1], cz = centre[p * 3 + 2];
        float h1r = fmaxf(sbsp2[lane] + cx * sWsp2t[0][lane] + cy * sWsp2t[1][lane]
                          + cz * sWsp2t[2][lane], 0.f);
        float mval = 0.f;
        if (lane < 32) {
            float c0 = corner[p*9+0], c1 = corner[p*9+1], c2 = corner[p*9+2];
            float c3 = corner[p*9+3], c4 = corner[p*9+4], c5 = corner[p*9+5];
            float c6 = corner[p*9+6], c7 = corner[p*9+7], c8 = corner[p*9+8];
            float s0 = c0 + c3 + c6, s1 = c1 + c4 + c7, s2 = c2 + c5 + c8;
            mval = sconvb[lane] + (1.f / 3.f) *
                ((sconvt[0][lane] + sconvt[3][lane]) * s0 +
                 (sconvt[1][lane] + sconvt[4][lane]) * s1 +
                 (sconvt[2][lane] + sconvt[5][lane]) * s2);
        }
        float h3 = sbfr3[lane];
#pragma unroll 8
        for (int k = 0; k < 32; ++k) h3 += __shfl(mval, k) * sWfr3t[k][lane];
        float h3r = fmaxf(h3, 0.f);
        int nb0 = clampi(neighbour[p * 3]), nb1 = clampi(neighbour[p * 3 + 1]), nb2 = clampi(neighbour[p * 3 + 2]);
        float nx[4], ny[4], nz[4];
        nx[0] = normal[p * 3];          ny[0] = normal[p * 3 + 1];          nz[0] = normal[p * 3 + 2];
        nx[1] = normal[(long)nb0 * 3];  ny[1] = normal[(long)nb0 * 3 + 1];  nz[1] = normal[(long)nb0 * 3 + 2];
        nx[2] = normal[(long)nb1 * 3];  ny[2] = normal[(long)nb1 * 3 + 1];  nz[2] = normal[(long)nb1 * 3 + 2];
        nx[3] = normal[(long)nb2 * 3];  ny[3] = normal[(long)nb2 * 3 + 1];  nz[3] = normal[(long)nb2 * 3 + 2];
        float kcs = 0.f;
#pragma unroll
        for (int s = 0; s < 4; ++s) {
            float kx = kt4x[s][lane], ky = kt4y[s][lane], kz = kt4z[s][lane];
#pragma unroll
            for (int t = 0; t < 4; ++t) {
                float dx = nx[t] - kx, dy = ny[t] - ky, dz = nz[t] - kz;
                kcs += __expf(-12.5f * (dx * dx + dy * dy + dz * dz));
            }
        }
        float kcv = kcs * (1.f / 16.f);
        row[lane] = f2bf(h1r); row[64 + lane] = f2bf(h3r); row[128 + lane] = f2bf(kcv);
        if (lane < 32) {
            float nrmv = (lane == 0) ? nx[0] : (lane == 1) ? ny[0] : (lane == 2) ? nz[0] : 0.f;
            row[192 + lane] = f2bf(nrmv);
        }
    }
}

// ---------------------------------------------------------------------------
// mega1: b<256 foldrhs | b<640 vecfolds | b<644 g_enc init |
//        b<836 L1 GEMM (T3 = M3@Wfa + M2 (8 colblk) || B2f = Wfb@W_a2 (4)) |
//        else featurize (2048 blocks)
// ---------------------------------------------------------------------------
__global__ __launch_bounds__(256) void mega1(
    const float* __restrict__ W_c1, const float* __restrict__ W_a1,
    const float* __restrict__ W_sp1, const float* __restrict__ W_fr4,
    const float* __restrict__ W_f,
    const float* __restrict__ b_sp1, const float* __restrict__ b_fr4,
    const float* __restrict__ b_c1, const float* __restrict__ b_a1,
    const float* __restrict__ b_f, const float* __restrict__ b_a2,
    float* __restrict__ Wc1ff, float* __restrict__ Wa1ff,
    float* __restrict__ bc1v, float* __restrict__ b_a1p, float* __restrict__ w2,
    unsigned* __restrict__ g_enc,
    const float* __restrict__ W_m2, const float* __restrict__ W_a2,
    float* __restrict__ T3f, float* __restrict__ B2f,
    const float* __restrict__ centre, const float* __restrict__ corner,
    const float* __restrict__ normal, const int* __restrict__ neighbour,
    const float* __restrict__ W_sp2, const float* __restrict__ b_sp2,
    const float* __restrict__ conv_w, const float* __restrict__ conv_b,
    const float* __restrict__ W_fr3, const float* __restrict__ b_fr3,
    const float* __restrict__ theta, const float* __restrict__ phi,
    __hip_bfloat16* __restrict__ cat1)
{
    const int b = blockIdx.x, t = threadIdx.x;
    if (b >= 836) {
        featurize_body(centre, corner, normal, neighbour, W_sp2, b_sp2,
                       conv_w, conv_b, W_fr3, b_fr3, theta, phi, cat1, b - 836, 2048);
        return;
    }
    if (b < 256) {
        const int r = b;
        float vc, va;
        if (t < 64) {
            float s = 0.f;
            for (int k = 0; k < 64; ++k) s += W_c1[r * 195 + k] * W_sp1[k * 64 + t];
            vc = s;
            s = 0.f;
            for (int k = 0; k < 64; ++k) s += W_a1[r * 131 + k] * W_fr4[k * 64 + t];
            va = s;
        } else if (t < 128) {
            float s = 0.f;
            for (int k = 0; k < 64; ++k) s += W_c1[r * 195 + 64 + k] * W_fr4[k * 64 + (t - 64)];
            vc = s;
            va = W_a1[r * 131 + t];
        } else {
            vc = (t < 195) ? W_c1[r * 195 + t] : 0.f;
            va = (t < 131) ? W_a1[r * 131 + t] : 0.f;
        }
        Wc1ff[r * 256 + t] = vc;
        Wa1ff[r * 256 + t] = va;
    } else if (b < 640) {
        int o = (b - 256) * 4 + (t >> 6);
        int lane = t & 63;
        float a = 0.f;
        if (o < 256) {
            a = W_c1[o * 195 + lane] * b_sp1[lane] + W_c1[o * 195 + 64 + lane] * b_fr4[lane];
        } else if (o < 512) {
            a = W_a1[(o - 256) * 131 + lane] * b_fr4[lane];
        } else {
            for (int k = lane; k < 512; k += 64) a += W_f[(long)(o - 512) * 1024 + 512 + k] * b_a2[k];
        }
#pragma unroll
        for (int off = 32; off > 0; off >>= 1) a += __shfl_xor(a, off);
        if (lane == 0) {
            if (o < 256)      bc1v[o] = b_c1[o] + a;
            else if (o < 512) b_a1p[o - 256] = b_a1[o - 256] + a;
            else              w2[o - 512] = b_f[o - 512] + a;
        }
    } else if (b < 644) {
        g_enc[(b - 640) * 256 + t] = 0x007FFFFFu;
    } else {
        __shared__ float sA[16][68], sB[16][68];
        int idx = b - 644, bj = idx % 12, bi = idx / 12;
        if (bj < 8)
            wg_body(W_m2 + 768, 1792, W_f, 1024, W_m2 + 256, 1792, 512,
                    T3f, (__hip_bfloat16*)nullptr, 512, 1024, 512, 0, bj, bi, t, sA, sB);
        else
            wg_body(W_f + 512, 1024, W_a2, 256, (const float*)nullptr, 0, 0,
                    B2f, (__hip_bfloat16*)nullptr, 256, 512, 256, 0, bj - 8, bi, t, sA, sB);
    }
}

// ---------------------------------------------------------------------------
// mega2: id<192 -> L2 (U = T3@W_c2 + [M1|0] (8 colblk) || Vf = M3@B2f (4))
//        else   -> gather1 full (3128 blocks, 16 points each)
// ---------------------------------------------------------------------------
__global__ __launch_bounds__(256) void mega2(
    const float* __restrict__ T3f, const float* __restrict__ W_c2,
    const float* __restrict__ W_m2, const float* __restrict__ B2f,
    float* __restrict__ Uf, float* __restrict__ Vf,
    const __hip_bfloat16* __restrict__ cat1, const int* __restrict__ neighbour,
    __hip_bfloat16* __restrict__ agg1)
{
    const int id = blockIdx.x, t = threadIdx.x;
    if (id < 192) {
        __shared__ float sA[16][68], sB[16][68];
        int bj = id % 12, bi = id / 12;
        if (bj < 8)
            wg_body(T3f, 512, W_c2, 512, W_m2, 1792, 256,
                    Uf, (__hip_bfloat16*)nullptr, 512, 512, 512, 0, bj, bi, t, sA, sB);
        else
            wg_body(W_m2 + 768, 1792, B2f, 256, (const float*)nullptr, 0, 0,
                    Vf, (__hip_bfloat16*)nullptr, 256, 1024, 256, 0, bj - 8, bi, t, sA, sB);
    } else {
        long pbase = (long)(id - 192) * 16 + (t >> 6) * 4;
        gather1_body4(cat1, neighbour, agg1, pbase, t & 63);
    }
}

// ---------------------------------------------------------------------------
// mega3: id<416 -> L3 (X1'/X2'/V' -> Xw) + cvec; else gather1t full (3128)
// ---------------------------------------------------------------------------
__global__ __launch_bounds__(256) void mega3(
    const float* __restrict__ Uf, const float* __restrict__ Vf,
    const float* __restrict__ Wc1ff, const float* __restrict__ Wa1ff,
    __hip_bfloat16* __restrict__ Xw,
    const float* __restrict__ W_m2, const float* __restrict__ T3f,
    const float* __restrict__ w2, const float* __restrict__ b_c2,
    const float* __restrict__ bc1v, const float* __restrict__ b_a1p,
    float* __restrict__ cvec,
    const __hip_bfloat16* __restrict__ agg1, const int* __restrict__ neighbour,
    __hip_bfloat16* __restrict__ agg1t)
{
    const int id = blockIdx.x, t = threadIdx.x;
    if (id >= 416) {
        long pbase = (long)(id - 416) * 16 + (t >> 6) * 4;
        gather1t_body4(agg1, neighbour, agg1t, pbase, t & 63);
        return;
    }
    __shared__ float sA[16][68], sB[16][68];
    const int bx = id % 26, bi = id / 26;
    if (bx < 4) {
        wg_body(Uf, 512, Wc1ff, 256, (const float*)nullptr, 0, 0,
                (float*)nullptr, Xw, 576, 256, 224, 0, bx, bi, t, sA, sB);
    } else if (bx < 7) {
        wg_body(Uf + 256, 512, Wa1ff, 256, (const float*)nullptr, 0, 0,
                (float*)nullptr, Xw + 224, 576, 256, 160, 0, bx - 4, bi, t, sA, sB);
    } else if (bx < 10) {
        // V' -> Xw cols 384:544, zero-fill cols 544:576 (zf=1)
        wg_body(Vf, 256, Wa1ff, 256, (const float*)nullptr, 0, 0,
                (float*)nullptr, Xw + 384, 576, 256, 160, 1, bx - 7, bi, t, sA, sB);
    } else {
        int i = ((bx - 10) * 16 + bi) * 4 + (t >> 6);
        int lane = t & 63;
        const float* m3row = W_m2 + (long)i * 1792 + 768;
        float a = 0.f;
        for (int k = lane; k < 1024; k += 64) a += w2[k] * m3row[k];
        for (int k = lane; k < 512;  k += 64) a += b_c2[k] * T3f[(long)i * 512 + k];
        for (int k = lane; k < 256;  k += 64) a += bc1v[k] * Uf[(long)i * 512 + k];
        for (int k = lane; k < 256;  k += 64) a += b_a1p[k] * Uf[(long)i * 512 + 256 + k];
        for (int k = lane; k < 256;  k += 64) a += b_a1p[k] * Vf[(long)i * 256 + k];
#pragma unroll
        for (int off = 32; off > 0; off >>= 1) a += __shfl_xor(a, off);
        if (lane == 0) cvec[i] = a;
    }
}

// ---------------------------------------------------------------------------
// max-GEMM (R12 version): A0=cat1(ld224, k<224), A1=agg1(ld160, k<384),
// A2=agg1t(ld192), B=Xw(ld576), K=576. XCD-swizzled 1D grid, async staging.
// ---------------------------------------------------------------------------
__global__ __launch_bounds__(256) void gemm_nt_max576(
    const __hip_bfloat16* __restrict__ A0,
    const __hip_bfloat16* __restrict__ A1,
    const __hip_bfloat16* __restrict__ A2,
    const __hip_bfloat16* __restrict__ B,
    unsigned* __restrict__ g_enc)
{
    __shared__ __align__(16) u16 Asm[2 * 128 * 32];
    __shared__ __align__(16) u16 Bsm[2 * 128 * 32];
    __shared__ float red[2][128];
    const int id = blockIdx.x;
    const int c = id & 7, tt = id >> 3;
    const int j8 = tt & 7, rh = tt >> 3;
    const int r = rh * 8 + c;
    if (r >= NPAD / 128) return;
    const long rowbase = (long)r * 128;
    const int colbase = j8 * 128;
    const int tid = threadIdx.x;
    const int lane = tid & 63, wave = tid >> 6;
    const int wr = wave >> 1, wc = wave & 1;
    const int m16 = lane & 15, kg = lane >> 4;
    const int srow = tid >> 2, skc = tid & 3;
    f32x4 acc[4][4] = {};
#pragma unroll
    for (int kt = 0; kt < 576; kt += 64) {
#pragma unroll
        for (int h = 0; h < 2; ++h) {
            const int kh = kt + h * 32;
#pragma unroll
            for (int i = 0; i < 2; ++i) {
                const int cid = i * 256 + tid;
                const int row = srow + i * 64, kc = skc;
                const __hip_bfloat16* Ap; long lda; int kl;
                if (kh < 224)      { Ap = A0; lda = 224; kl = kh; }
                else if (kh < 384) { Ap = A1; lda = 160; kl = kh - 224; }
                else               { Ap = A2; lda = 192; kl = kh - 384; }
                gload_lds16(Ap + (rowbase + row) * lda + kl + kc * 8, Asm + h * 4096 + cid * 8);
                gload_lds16(B + (long)(colbase + row) * 576 + kh + kc * 8, Bsm + h * 4096 + cid * 8);
            }
        }
        __syncthreads();
#pragma unroll
        for (int h = 0; h < 2; ++h) {
            bf16x8 af[4], bv[4];
#pragma unroll
            for (int i = 0; i < 4; ++i)
                af[i] = *(const bf16x8*)(Asm + h * 4096 + ((wr * 64 + i * 16 + m16) * 32 + kg * 8));
#pragma unroll
            for (int j = 0; j < 4; ++j)
                bv[j] = *(const bf16x8*)(Bsm + h * 4096 + ((wc * 64 + j * 16 + m16) * 32 + kg * 8));
#pragma unroll
            for (int i = 0; i < 4; ++i)
#pragma unroll
                for (int j = 0; j < 4; ++j)
                    acc[i][j] = __builtin_amdgcn_mfma_f32_16x16x32_bf16(af[i], bv[j], acc[i][j], 0, 0, 0);
        }
        __syncthreads();
    }
    const int q = lane >> 4;
#pragma unroll
    for (int j = 0; j < 4; ++j) {
        float m = -INFINITY;
#pragma unroll
        for (int i = 0; i < 4; ++i)
#pragma unroll
            for (int rr = 0; rr < 4; ++rr) {
                long rowg = rowbase + wr * 64 + i * 16 + q * 4 + rr;
                m = (rowg < NPTS) ? fmaxf(m, acc[i][j][rr]) : m;
            }
        m = fmaxf(m, __shfl_xor(m, 16));
        m = fmaxf(m, __shfl_xor(m, 32));
        if (lane < 16) red[wr][wc * 64 + j * 16 + m16] = m;
    }
    __syncthreads();
    if (tid < 128) {
        float v = fmaxf(red[0][tid], red[1][tid]);
        atomicMax(g_enc + colbase + tid, enc_f32(v));
    }
}

// ---------------------------------------------------------------------------
// head
// ---------------------------------------------------------------------------
__global__ __launch_bounds__(256) void head_lin_g(
    const unsigned* __restrict__ g_enc, const float* __restrict__ cvec,
    const float* __restrict__ b_m2,
    const float* __restrict__ W, const float* __restrict__ b,
    float* __restrict__ out)
{
    int o = blockIdx.x * 4 + (threadIdx.x >> 6);
    int lane = threadIdx.x & 63;
    if (o >= 512) return;
    float a = 0.f;
    for (int k = lane; k < 1024; k += 64) {
        float g = dec_f32(g_enc[k]) + cvec[k] + b_m2[k];
        a += g * W[(long)o * 1024 + k];
    }
#pragma unroll
    for (int off = 32; off > 0; off >>= 1) a += __shfl_xor(a, off);
    if (lane == 0) out[o] = fmaxf(a + b[o], 0.f);
}

__global__ __launch_bounds__(256) void head_lin(
    const float* __restrict__ in, const float* __restrict__ W,
    const float* __restrict__ b, float* __restrict__ out,
    int In, int Out, int do_relu)
{
    int o = blockIdx.x * 4 + (threadIdx.x >> 6);
    int lane = threadIdx.x & 63;
    if (o >= Out) return;
    float a = 0.f;
    for (int k = lane; k < In; k += 64) a += in[k] * W[(long)o * In + k];
#pragma unroll
    for (int off = 32; off > 0; off >>= 1) a += __shfl_xor(a, off);
    if (lane == 0) {
        float v = a + b[o];
        out[o] = do_relu ? fmaxf(v, 0.f) : v;
    }
}

// ---------------------------------------------------------------------------
extern "C" void kernel_launch(void* const* d_in, const int* in_sizes, int n_in,
                              void* d_out, int out_size, void* d_ws, size_t ws_size,
                              hipStream_t stream)
{
    (void)in_sizes; (void)n_in; (void)out_size; (void)ws_size;
    const float* centre = (const float*)d_in[0];
    const float* corner = (const float*)d_in[1];
    const float* normal = (const float*)d_in[2];
    const int*   neighbour = (const int*)d_in[3];
    const float* W_sp2 = (const float*)d_in[4];
    const float* b_sp2 = (const float*)d_in[5];
    const float* W_sp1 = (const float*)d_in[6];
    const float* b_sp1 = (const float*)d_in[7];
    const float* conv_w = (const float*)d_in[8];
    const float* conv_b = (const float*)d_in[9];
    const float* W_fr3 = (const float*)d_in[10];
    const float* b_fr3 = (const float*)d_in[11];
    const float* W_fr4 = (const float*)d_in[12];
    const float* b_fr4 = (const float*)d_in[13];
    const float* theta = (const float*)d_in[14];
    const float* phi   = (const float*)d_in[15];
    const float* W_c1 = (const float*)d_in[16];
    const float* b_c1 = (const float*)d_in[17];
    const float* W_a1 = (const float*)d_in[18];
    const float* b_a1 = (const float*)d_in[19];
    const float* W_c2 = (const float*)d_in[20];
    const float* b_c2 = (const float*)d_in[21];
    const float* W_a2 = (const float*)d_in[22];
    const float* b_a2 = (const float*)d_in[23];
    const float* W_f  = (const float*)d_in[24];
    const float* b_f  = (const float*)d_in[25];
    const float* W_m2 = (const float*)d_in[26];
    const float* b_m2 = (const float*)d_in[27];
    const float* W_m31 = (const float*)d_in[28];
    const float* b_m31 = (const float*)d_in[29];
    const float* W_m32 = (const float*)d_in[30];
    const float* b_m32 = (const float*)d_in[31];
    const float* W_m33 = (const float*)d_in[32];
    const float* b_m33 = (const float*)d_in[33];

    char* ws = (char*)d_ws;
    size_t off = 0;
    auto alloc = [&](size_t bytes) { void* p = ws + off; off += (bytes + 255) & ~(size_t)255; return p; };
    __hip_bfloat16* cat1  = (__hip_bfloat16*)alloc((size_t)NPAD * 224 * 2);  // [h1r|h3r|kc|nrm+pad]
    __hip_bfloat16* agg1  = (__hip_bfloat16*)alloc((size_t)NPAD * 160 * 2);  // 1-hop avg
    __hip_bfloat16* agg1t = (__hip_bfloat16*)alloc((size_t)NPAD * 192 * 2);  // 2-hop avg + zero pad
    float* Wc1ff = (float*)alloc((size_t)65536 * 4);
    float* Wa1ff = (float*)alloc((size_t)65536 * 4);
    __hip_bfloat16* Xw = (__hip_bfloat16*)alloc((size_t)1024 * 576 * 2);     // [X1'(224)|X2'(160)|V'(160)|0(32)]
    float* T3f  = (float*)alloc((size_t)1024 * 512 * 4);
    float* Uf   = (float*)alloc((size_t)1024 * 512 * 4);                     // [U1|U2]
    float* B2f  = (float*)alloc((size_t)1024 * 256 * 4);
    float* Vf   = (float*)alloc((size_t)1024 * 256 * 4);
    float* bc1v = (float*)alloc(256 * 4);
    float* b_a1p = (float*)alloc(256 * 4);
    float* w2   = (float*)alloc(1024 * 4);
    float* cvec = (float*)alloc(1024 * 4);
    unsigned* g_enc = (unsigned*)alloc(1024 * 4);
    float* h1   = (float*)alloc(512 * 4);
    float* h2   = (float*)alloc(256 * 4);

    // 1) folds + g_enc + L1 (T3, B2f) || featurize
    mega1<<<2884, 256, 0, stream>>>(W_c1, W_a1, W_sp1, W_fr4, W_f,
        b_sp1, b_fr4, b_c1, b_a1, b_f, b_a2,
        Wc1ff, Wa1ff, bc1v, b_a1p, w2, g_enc,
        W_m2, W_a2, T3f, B2f,
        centre, corner, normal, neighbour, W_sp2, b_sp2,
        conv_w, conv_b, W_fr3, b_fr3, theta, phi, cat1);
    // 2) L2 (U, Vf) || gather1 full
    mega2<<<192 + 3128, 256, 0, stream>>>(T3f, W_c2, W_m2, B2f, Uf, Vf,
        cat1, neighbour, agg1);
    // 3) L3 (Xw) + cvec || gather1t full
    mega3<<<416 + 3128, 256, 0, stream>>>(Uf, Vf, Wc1ff, Wa1ff, Xw,
        W_m2, T3f, w2, b_c2, bc1v, b_a1p, cvec,
        agg1, neighbour, agg1t);
    // 4) g = max_n([cat1|agg1|agg1t] @ Xw^T), K=576, XCD-swizzled grid
    gemm_nt_max576<<<3136, 256, 0, stream>>>(cat1, agg1, agg1t, Xw, g_enc);
    // 5-7) head
    head_lin_g<<<128, 256, 0, stream>>>(g_enc, cvec, b_m2, W_m31, b_m31, h1);
    head_lin<<<64, 256, 0, stream>>>(h1, W_m32, b_m32, h2, 512, 256, 1);
    head_lin<<<10, 256, 0, stream>>>(h2, W_m33, b_m33, (float*)d_out, 256, 40, 0);
}